// Round 13
// baseline (622.779 us; speedup 1.0000x reference)
//
#include <hip/hip_runtime.h>

#define N_NODES  100000
#define N_EDGES  800000
#define ET       900000   // edges + self loops
#define N_GRAPHS 2000
#define IN_DIM   64
#define HID      32
#define HEADS    4
#define HF       128      // HEADS*HID
#define NEG_SLOPE 0.2f

typedef __attribute__((ext_vector_type(8))) short bf16x8;
typedef __attribute__((ext_vector_type(4))) float f32x4;

__device__ __forceinline__ float lrelu(float x) { return x > 0.f ? x : NEG_SLOPE * x; }
__device__ __forceinline__ float elu_f(float x) { return x > 0.f ? x : expm1f(x); }
// order-preserving float<->uint encode for atomicMax over signed floats
__device__ __forceinline__ unsigned fenc(float f) {
  unsigned u = __float_as_uint(f);
  return (u & 0x80000000u) ? ~u : (u | 0x80000000u);
}
__device__ __forceinline__ float fdec(unsigned e) {
  return __uint_as_float((e & 0x80000000u) ? (e ^ 0x80000000u) : ~e);
}
// round-to-nearest-even fp32 -> bf16 (bit trick)
__device__ __forceinline__ unsigned short bf16_rne(float f) {
  unsigned u = __float_as_uint(f);
  unsigned r = (u + 0x7fffu + ((u >> 16) & 1u)) >> 16;
  return (unsigned short)r;
}
// split two float4 (8 fp32) into hi/lo bf16x8 fragments
__device__ __forceinline__ void split8(const float4& a, const float4& b,
                                       bf16x8& hi, bf16x8& lo) {
  float xv[8] = {a.x, a.y, a.z, a.w, b.x, b.y, b.z, b.w};
#pragma unroll
  for (int j = 0; j < 8; ++j) {
    unsigned short h = bf16_rne(xv[j]);
    hi[j] = (short)h;
    lo[j] = (short)bf16_rne(xv[j] - __uint_as_float((unsigned)h << 16));
  }
}

// ---------------- CSR build ----------------
__global__ void k_count(const int* __restrict__ ei, int* __restrict__ deg) {
  int e = blockIdx.x * 256 + threadIdx.x;
  if (e >= ET) return;
  int d = (e < N_EDGES) ? ei[N_EDGES + e] : (e - N_EDGES);
  atomicAdd(&deg[d], 1);
}

__global__ void k_scan1(const int* __restrict__ deg, int* __restrict__ rs, int* __restrict__ bsums) {
  __shared__ int sd[256];
  int t = threadIdx.x;
  int i = blockIdx.x * 256 + t;
  int v = (i < N_NODES) ? deg[i] : 0;
  sd[t] = v; __syncthreads();
  for (int s = 1; s < 256; s <<= 1) {
    int tmp = (t >= s) ? sd[t - s] : 0; __syncthreads();
    sd[t] += tmp; __syncthreads();
  }
  if (i < N_NODES) rs[i] = sd[t] - v;
  if (t == 255) bsums[blockIdx.x] = sd[255];
}

__global__ void k_scan2(int* __restrict__ bsums, int nb) {
  __shared__ int sd[512];
  int t = threadIdx.x;
  int v = (t < nb) ? bsums[t] : 0;
  sd[t] = v; __syncthreads();
  for (int s = 1; s < 512; s <<= 1) {
    int tmp = (t >= s) ? sd[t - s] : 0; __syncthreads();
    sd[t] += tmp; __syncthreads();
  }
  if (t < nb) bsums[t] = sd[t] - v;
}

__global__ void k_scan3(int* __restrict__ rs, const int* __restrict__ bsums) {
  int i = blockIdx.x * 256 + threadIdx.x;
  if (i < N_NODES) rs[i] += bsums[blockIdx.x];
  if (i == 0) rs[N_NODES] = ET;
}

__global__ void k_fill(const int* __restrict__ ei, const int* __restrict__ rs,
                       int* __restrict__ fill, int* __restrict__ csr_src) {
  int e = blockIdx.x * 256 + threadIdx.x;
  if (e >= ET) return;
  int s, d;
  if (e < N_EDGES) { s = ei[e]; d = ei[N_EDGES + e]; }
  else             { s = e - N_EDGES; d = s; }
  int pos = atomicAdd(&fill[d], 1);
  csr_src[rs[d] + pos] = s;
}

// ---------------- weight prep: pack [W | W.a_src | W.a_dst | 0] (144 cols),
// split fp32 -> bf16 hi/lo, store in MFMA B-fragment layout [k/8][c][k&7] ----
template<int K>
__global__ void k_prep(const float* __restrict__ W, const float* __restrict__ as_,
                       const float* __restrict__ ad_,
                       unsigned short* __restrict__ Bh, unsigned short* __restrict__ Bl) {
  int idx = blockIdx.x * 256 + threadIdx.x;
  if (idx >= K * 144) return;
  int k = idx / 144, c = idx % 144;
  float v = 0.f;
  if (c < 128) {
    v = W[k * 128 + c];
  } else if (c < 136) {
    int h = (c - 128) & 3;
    const float* av = (c < 132) ? as_ : ad_;
    float s = 0.f;
    for (int f = 0; f < HID; ++f) s += W[k * 128 + h * HID + f] * av[h * HID + f];
    v = s;
  }
  unsigned short hi = bf16_rne(v);
  float hf = __uint_as_float((unsigned)hi << 16);
  unsigned short lo = bf16_rne(v - hf);
  size_t dst = ((size_t)(k >> 3) * 144 + c) * 8 + (k & 7);
  Bh[dst] = hi;
  Bl[dst] = lo;
}

// ---------------- MFMA GEMM (split-bf16) + fused attention cols + AS max ----
// Inner loop restructured m97-style: ALL 18 B-fragment ds_reads issued as a
// burst into registers, THEN the 27-MFMA cluster (staggered lgkmcnt instead
// of per-tile drain). Wave tile 16 rows x 144 cols; B staged per 64-k half.
template<int K>
__global__ void __launch_bounds__(256, 3) k_gemm_attn(
    const float* __restrict__ X,
    const unsigned short* __restrict__ Bh, const unsigned short* __restrict__ Bl,
    float* __restrict__ H, float* __restrict__ AS, float* __restrict__ AD,
    unsigned* __restrict__ M4) {
  __shared__ short sBh[64 * 144];      // 18.4 KB
  __shared__ short sBl[64 * 144];      // total 36.9 KB
  const int t = threadIdx.x;
  const int l = t & 63;
  const int m = l & 15;                 // A-row / B-col / D-col selector
  const int g = l >> 4;                 // k-group selector (8 k per group)
  const int row0 = blockIdx.x * 64 + (t >> 6) * 16;  // this wave's 16 rows
  const int arow = row0 + m;
  // clamped pointer: rows >= N read row N-1 (valid memory; stores guarded)
  const float* xrow = &X[(size_t)min(arow, N_NODES - 1) * K];

  f32x4 acc[9];
#pragma unroll
  for (int b = 0; b < 9; ++b) acc[b] = (f32x4){0.f, 0.f, 0.f, 0.f};

  // depth-1 A prefetch
  float4 pxa = *(const float4*)&xrow[g * 8];
  float4 pxb = *(const float4*)&xrow[g * 8 + 4];

  for (int h = 0; h < K / 64; ++h) {
    __syncthreads();                   // previous half's compute done
    for (int i = t; i < 1152; i += 256) {
      ((bf16x8*)sBh)[i] = ((const bf16x8*)Bh)[h * 1152 + i];
      ((bf16x8*)sBl)[i] = ((const bf16x8*)Bl)[h * 1152 + i];
    }
    __syncthreads();                   // LDS ready
#pragma unroll
    for (int cc = 0; cc < 2; ++cc) {   // two 32-k chunks per half
      bf16x8 ahi, alo;
      split8(pxa, pxb, ahi, alo);
      int kn = h * 64 + cc * 32 + 32;  // next chunk's base
      if (kn < K) {                    // issue next loads under this compute
        pxa = *(const float4*)&xrow[kn + g * 8];
        pxb = *(const float4*)&xrow[kn + g * 8 + 4];
      }
      const int kfl = (cc * 4 + g) * 144;   // half-local fragment row
      // burst-load ALL 18 B fragments (compile-time indices -> registers)
      bf16x8 bhv[9], blv[9];
#pragma unroll
      for (int tc = 0; tc < 9; ++tc) {
        bhv[tc] = *(const bf16x8*)(sBh + (kfl + tc * 16 + m) * 8);
        blv[tc] = *(const bf16x8*)(sBl + (kfl + tc * 16 + m) * 8);
      }
      // MFMA cluster: 27 ops, 9 independent chains
#pragma unroll
      for (int tc = 0; tc < 9; ++tc)
        acc[tc] = __builtin_amdgcn_mfma_f32_16x16x32_bf16(ahi, bhv[tc], acc[tc], 0, 0, 0);
#pragma unroll
      for (int tc = 0; tc < 9; ++tc) {
        acc[tc] = __builtin_amdgcn_mfma_f32_16x16x32_bf16(ahi, blv[tc], acc[tc], 0, 0, 0);
        acc[tc] = __builtin_amdgcn_mfma_f32_16x16x32_bf16(alo, bhv[tc], acc[tc], 0, 0, 0);
      }
    }
  }

  // epilogue: D layout col = m, row = g*4 + e (m89-verified)
  const int rbase = row0 + g * 4;
  float vmax = -3.4e38f;
#pragma unroll
  for (int tc = 0; tc < 8; ++tc) {
    int col = tc * 16 + m;
#pragma unroll
    for (int e = 0; e < 4; ++e) {
      int r = rbase + e;
      if (r < N_NODES) H[(size_t)r * HF + col] = acc[tc][e];
    }
  }
  // attention tile (tc==8): cols 0-3 = AS heads, 4-7 = AD heads
#pragma unroll
  for (int e = 0; e < 4; ++e) {
    int r = rbase + e;
    float v = acc[8][e];
    if (r < N_NODES) {
      if (m < 4) AS[r * HEADS + m] = v;
      else if (m < 8) AD[r * HEADS + (m - 4)] = v;
    }
    vmax = fmaxf(vmax, v);   // clamped pad rows duplicate a real row: bound stays valid
  }
  // per-head AS max -> M4 (fold g via shuffles, then 4 atomics per wave)
  vmax = fmaxf(vmax, __shfl_xor(vmax, 16));
  vmax = fmaxf(vmax, __shfl_xor(vmax, 32));
  if (g == 0 && m < 4) atomicMax(&M4[m], fenc(vmax));
}

// ---------------- fused softmax + aggregation ----------------
// Half-wave (32 lanes) per node: each lane owns 4 columns (float4) of the
// 512B H row. 4 edges unrolled -> independent csr->H gather chains.
template<bool CONCAT>
__global__ void __launch_bounds__(256) k_aggregate(
    const int* __restrict__ rs, const int* __restrict__ csr_src,
    const float* __restrict__ H, const float* __restrict__ AS,
    const float* __restrict__ AD, const unsigned* __restrict__ M4,
    const float* __restrict__ bias, float* __restrict__ OUT) {
  int n = blockIdx.x * 8 + (threadIdx.x >> 5);
  if (n >= N_NODES) return;
  int sl = threadIdx.x & 31;
  int c = sl * 4;                      // this lane's 4 columns
  int head = sl >> 3;
  int b = rs[n], e = rs[n + 1];

  float ad = AD[4 * n + head];
  float m = lrelu(fdec(M4[head]) + ad);

  float ax = 0.f, ay = 0.f, az = 0.f, aw = 0.f, den = 0.f;
  int jj = b;
  for (; jj + 3 < e; jj += 4) {        // 4 gather chains in flight
    int s0 = csr_src[jj];
    int s1 = csr_src[jj + 1];
    int s2 = csr_src[jj + 2];
    int s3 = csr_src[jj + 3];
    float e0 = __expf(lrelu(AS[4 * s0 + head] + ad) - m);
    float e1 = __expf(lrelu(AS[4 * s1 + head] + ad) - m);
    float e2 = __expf(lrelu(AS[4 * s2 + head] + ad) - m);
    float e3 = __expf(lrelu(AS[4 * s3 + head] + ad) - m);
    float4 h0 = *(const float4*)&H[(size_t)s0 * HF + c];
    float4 h1 = *(const float4*)&H[(size_t)s1 * HF + c];
    float4 h2 = *(const float4*)&H[(size_t)s2 * HF + c];
    float4 h3 = *(const float4*)&H[(size_t)s3 * HF + c];
    ax += h0.x * e0 + h1.x * e1 + h2.x * e2 + h3.x * e3;
    ay += h0.y * e0 + h1.y * e1 + h2.y * e2 + h3.y * e3;
    az += h0.z * e0 + h1.z * e1 + h2.z * e2 + h3.z * e3;
    aw += h0.w * e0 + h1.w * e1 + h2.w * e2 + h3.w * e3;
    den += (e0 + e1) + (e2 + e3);
  }
  for (; jj < e; ++jj) {
    int s0 = csr_src[jj];
    float e0 = __expf(lrelu(AS[4 * s0 + head] + ad) - m);
    float4 h0 = *(const float4*)&H[(size_t)s0 * HF + c];
    ax += h0.x * e0; ay += h0.y * e0; az += h0.z * e0; aw += h0.w * e0;
    den += e0;
  }

  float invd = 1.f / den;
  if (CONCAT) {
    float4 o;
    o.x = elu_f(ax * invd + bias[c]);
    o.y = elu_f(ay * invd + bias[c + 1]);
    o.z = elu_f(az * invd + bias[c + 2]);
    o.w = elu_f(aw * invd + bias[c + 3]);
    *(float4*)&OUT[(size_t)n * HF + c] = o;
  } else {
    // mean over heads: fold lanes sl^8, sl^16 (stay within the 32-lane half)
    ax *= invd; ay *= invd; az *= invd; aw *= invd;
    ax += __shfl_xor(ax, 8);  ay += __shfl_xor(ay, 8);
    az += __shfl_xor(az, 8);  aw += __shfl_xor(aw, 8);
    ax += __shfl_xor(ax, 16); ay += __shfl_xor(ay, 16);
    az += __shfl_xor(az, 16); aw += __shfl_xor(aw, 16);
    if (sl < 8) {
      int cc = sl * 4;                 // 0..28
      float4 o;
      o.x = elu_f(0.25f * ax + bias[cc]);
      o.y = elu_f(0.25f * ay + bias[cc + 1]);
      o.z = elu_f(0.25f * az + bias[cc + 2]);
      o.w = elu_f(0.25f * aw + bias[cc + 3]);
      *(float4*)&OUT[(size_t)n * HID + cc] = o;
    }
  }
}

// ---------------- global mean pool + MLP head (one wave per graph) ----------------
__global__ void __launch_bounds__(64) k_pool_mlp(
    const int* __restrict__ batch, const float* __restrict__ H3,
    const float* __restrict__ Wm1, const float* __restrict__ bm1,
    const float* __restrict__ Wm2, const float* __restrict__ bm2,
    float* __restrict__ OUT) {
  int g = blockIdx.x;
  int t = threadIdx.x;
  __shared__ float pooled[HID];
  int lo = 0, hi = N_NODES;
  while (lo < hi) { int mid = (lo + hi) >> 1; if (batch[mid] < g) lo = mid + 1; else hi = mid; }
  int start = lo;
  hi = N_NODES;
  while (lo < hi) { int mid = (lo + hi) >> 1; if (batch[mid] < g + 1) lo = mid + 1; else hi = mid; }
  int end = lo;
  if (t < HID) {
    float s = 0.f;
    for (int n = start; n < end; ++n) s += H3[(size_t)n * HID + t];
    float cnt = (float)(end - start);
    pooled[t] = s / fmaxf(cnt, 1.f);
  }
  __syncthreads();
  float z = bm1[t];
#pragma unroll
  for (int f = 0; f < HID; ++f) z += pooled[f] * Wm1[f * 64 + t];
  z = fmaxf(z, 0.f);
  float p = z * Wm2[t];
  for (int off = 32; off > 0; off >>= 1) p += __shfl_down(p, off);
  if (t == 0) OUT[g] = p + bm2[0];
}

extern "C" void kernel_launch(void* const* d_in, const int* in_sizes, int n_in,
                              void* d_out, int out_size, void* d_ws, size_t ws_size,
                              hipStream_t stream) {
  const float* x    = (const float*)d_in[0];
  const int*   ei   = (const int*)d_in[1];
  const int*   batch= (const int*)d_in[2];
  const float* W1   = (const float*)d_in[3];
  const float* a1s  = (const float*)d_in[4];
  const float* a1d  = (const float*)d_in[5];
  const float* b1   = (const float*)d_in[6];
  const float* W2   = (const float*)d_in[7];
  const float* a2s  = (const float*)d_in[8];
  const float* a2d  = (const float*)d_in[9];
  const float* b2   = (const float*)d_in[10];
  const float* W3   = (const float*)d_in[11];
  const float* a3s  = (const float*)d_in[12];
  const float* a3d  = (const float*)d_in[13];
  const float* b3   = (const float*)d_in[14];
  const float* Wm1  = (const float*)d_in[15];
  const float* bm1  = (const float*)d_in[16];
  const float* Wm2  = (const float*)d_in[17];
  const float* bm2  = (const float*)d_in[18];
  float* out = (float*)d_out;

  char* p = (char*)d_ws;
  auto take = [&](size_t bytes) { char* r = p; p += (bytes + 255) & ~(size_t)255; return r; };
  float*          bufA = (float*)take((size_t)N_NODES * HF * 4);
  float*          bufB = (float*)take((size_t)N_NODES * HF * 4);
  float*          AS   = (float*)take((size_t)N_NODES * HEADS * 4);
  float*          AD   = (float*)take((size_t)N_NODES * HEADS * 4);
  unsigned*       M4   = (unsigned*)take(3 * 4 * 4);        // 3 layers x 4 heads
  int*            deg  = (int*)take((size_t)N_NODES * 4);   // reused as fill counters
  int*            rs   = (int*)take((size_t)(N_NODES + 1) * 4);
  int*            csr  = (int*)take((size_t)ET * 4);
  int*            bsums= (int*)take((size_t)512 * 4);
  unsigned short* Wh1  = (unsigned short*)take((size_t)IN_DIM * 144 * 2);
  unsigned short* Wl1  = (unsigned short*)take((size_t)IN_DIM * 144 * 2);
  unsigned short* Wh2  = (unsigned short*)take((size_t)HF * 144 * 2);
  unsigned short* Wl2  = (unsigned short*)take((size_t)HF * 144 * 2);
  unsigned short* Wh3  = (unsigned short*)take((size_t)HF * 144 * 2);
  unsigned short* Wl3  = (unsigned short*)take((size_t)HF * 144 * 2);

  unsigned* M4a = M4;
  unsigned* M4b = M4 + 4;
  unsigned* M4c = M4 + 8;

  const int nb_scan = (N_NODES + 255) / 256;  // 391

  // weight prep (independent of CSR; tiny)
  k_prep<IN_DIM><<<(IN_DIM * 144 + 255) / 256, 256, 0, stream>>>(W1, a1s, a1d, Wh1, Wl1);
  k_prep<HF><<<(HF * 144 + 255) / 256, 256, 0, stream>>>(W2, a2s, a2d, Wh2, Wl2);
  k_prep<HF><<<(HF * 144 + 255) / 256, 256, 0, stream>>>(W3, a3s, a3d, Wh3, Wl3);

  hipMemsetAsync(deg, 0, (size_t)N_NODES * 4, stream);
  hipMemsetAsync(M4, 0, 48, stream);
  k_count<<<(ET + 255) / 256, 256, 0, stream>>>(ei, deg);
  k_scan1<<<nb_scan, 256, 0, stream>>>(deg, rs, bsums);
  k_scan2<<<1, 512, 0, stream>>>(bsums, nb_scan);
  k_scan3<<<nb_scan, 256, 0, stream>>>(rs, bsums);
  hipMemsetAsync(deg, 0, (size_t)N_NODES * 4, stream);
  k_fill<<<(ET + 255) / 256, 256, 0, stream>>>(ei, rs, deg, csr);

  const int gb = (N_NODES + 63) / 64;         // 1563 blocks of 64 rows
  const int ab = (N_NODES + 7) / 8;           // aggregate: 8 nodes/block

  // layer 1 (K=64)
  k_gemm_attn<IN_DIM><<<gb, 256, 0, stream>>>(x, Wh1, Wl1, bufA, AS, AD, M4a);
  k_aggregate<true><<<ab, 256, 0, stream>>>(rs, csr, bufA, AS, AD, M4a, b1, bufB);
  // layer 2 (K=128)
  k_gemm_attn<HF><<<gb, 256, 0, stream>>>(bufB, Wh2, Wl2, bufA, AS, AD, M4b);
  k_aggregate<true><<<ab, 256, 0, stream>>>(rs, csr, bufA, AS, AD, M4b, b2, bufB);
  // layer 3 (K=128, concat=False -> head mean)
  k_gemm_attn<HF><<<gb, 256, 0, stream>>>(bufB, Wh3, Wl3, bufA, AS, AD, M4c);
  k_aggregate<false><<<ab, 256, 0, stream>>>(rs, csr, bufA, AS, AD, M4c, b3, bufB);
  // pool + MLP
  k_pool_mlp<<<N_GRAPHS, 64, 0, stream>>>(batch, bufB, Wm1, bm1, Wm2, bm2, out);
}

// Round 14
// 518.527 us; speedup vs baseline: 1.2011x; 1.2011x over previous
//
#include <hip/hip_runtime.h>

#define N_NODES  100000
#define N_EDGES  800000
#define ET       900000   // edges + self loops
#define N_GRAPHS 2000
#define IN_DIM   64
#define HID      32
#define HEADS    4
#define HF       128      // HEADS*HID
#define NEG_SLOPE 0.2f

typedef __attribute__((ext_vector_type(8))) short bf16x8;
typedef __attribute__((ext_vector_type(4))) float f32x4;

__device__ __forceinline__ float lrelu(float x) { return x > 0.f ? x : NEG_SLOPE * x; }
__device__ __forceinline__ float elu_f(float x) { return x > 0.f ? x : expm1f(x); }
// order-preserving float<->uint encode for atomicMax over signed floats
__device__ __forceinline__ unsigned fenc(float f) {
  unsigned u = __float_as_uint(f);
  return (u & 0x80000000u) ? ~u : (u | 0x80000000u);
}
__device__ __forceinline__ float fdec(unsigned e) {
  return __uint_as_float((e & 0x80000000u) ? (e ^ 0x80000000u) : ~e);
}
// round-to-nearest-even fp32 -> bf16 (bit trick)
__device__ __forceinline__ unsigned short bf16_rne(float f) {
  unsigned u = __float_as_uint(f);
  unsigned r = (u + 0x7fffu + ((u >> 16) & 1u)) >> 16;
  return (unsigned short)r;
}

// ---------------- CSR build ----------------
__global__ void k_count(const int* __restrict__ ei, int* __restrict__ deg) {
  int e = blockIdx.x * 256 + threadIdx.x;
  if (e >= ET) return;
  int d = (e < N_EDGES) ? ei[N_EDGES + e] : (e - N_EDGES);
  atomicAdd(&deg[d], 1);
}

__global__ void k_scan1(const int* __restrict__ deg, int* __restrict__ rs, int* __restrict__ bsums) {
  __shared__ int sd[256];
  int t = threadIdx.x;
  int i = blockIdx.x * 256 + t;
  int v = (i < N_NODES) ? deg[i] : 0;
  sd[t] = v; __syncthreads();
  for (int s = 1; s < 256; s <<= 1) {
    int tmp = (t >= s) ? sd[t - s] : 0; __syncthreads();
    sd[t] += tmp; __syncthreads();
  }
  if (i < N_NODES) rs[i] = sd[t] - v;
  if (t == 255) bsums[blockIdx.x] = sd[255];
}

__global__ void k_scan2(int* __restrict__ bsums, int nb) {
  __shared__ int sd[512];
  int t = threadIdx.x;
  int v = (t < nb) ? bsums[t] : 0;
  sd[t] = v; __syncthreads();
  for (int s = 1; s < 512; s <<= 1) {
    int tmp = (t >= s) ? sd[t - s] : 0; __syncthreads();
    sd[t] += tmp; __syncthreads();
  }
  if (t < nb) bsums[t] = sd[t] - v;
}

__global__ void k_scan3(int* __restrict__ rs, const int* __restrict__ bsums) {
  int i = blockIdx.x * 256 + threadIdx.x;
  if (i < N_NODES) rs[i] += bsums[blockIdx.x];
  if (i == 0) rs[N_NODES] = ET;
}

__global__ void k_fill(const int* __restrict__ ei, const int* __restrict__ rs,
                       int* __restrict__ fill, int* __restrict__ csr_src) {
  int e = blockIdx.x * 256 + threadIdx.x;
  if (e >= ET) return;
  int s, d;
  if (e < N_EDGES) { s = ei[e]; d = ei[N_EDGES + e]; }
  else             { s = e - N_EDGES; d = s; }
  int pos = atomicAdd(&fill[d], 1);
  csr_src[rs[d] + pos] = s;
}

// ---------------- weight prep: pack [W | W.a_src | W.a_dst | 0] (144 cols),
// split fp32 -> bf16 hi/lo, store in MFMA B-fragment layout [k/8][c][k&7] ----
template<int K>
__global__ void k_prep(const float* __restrict__ W, const float* __restrict__ as_,
                       const float* __restrict__ ad_,
                       unsigned short* __restrict__ Bh, unsigned short* __restrict__ Bl) {
  int idx = blockIdx.x * 256 + threadIdx.x;
  if (idx >= K * 144) return;
  int k = idx / 144, c = idx % 144;
  float v = 0.f;
  if (c < 128) {
    v = W[k * 128 + c];
  } else if (c < 136) {
    int h = (c - 128) & 3;
    const float* av = (c < 132) ? as_ : ad_;
    float s = 0.f;
    for (int f = 0; f < HID; ++f) s += W[k * 128 + h * HID + f] * av[h * HID + f];
    v = s;
  }
  unsigned short hi = bf16_rne(v);
  float hf = __uint_as_float((unsigned)hi << 16);
  unsigned short lo = bf16_rne(v - hf);
  size_t dst = ((size_t)(k >> 3) * 144 + c) * 8 + (k & 7);
  Bh[dst] = hi;
  Bl[dst] = lo;
}

// ---------------- MFMA GEMM (split-bf16) + fused attention cols + AS max ----
// B (hi+lo, fragment layout) staged ONCE into LDS per block; barrier-free
// K-loop with depth-1 A prefetch. EPILOGUE: accumulators bounced through
// LDS (B region is dead post-loop) so ALL H/AS/AD stores are full-line
// lane-consecutive float4 wave-stores (theory: partial-line scatter stores
// were the 72-95us floor).
template<int K>
__global__ void __launch_bounds__(256, 4) k_gemm_attn(
    const float* __restrict__ X,
    const unsigned short* __restrict__ Bh, const unsigned short* __restrict__ Bl,
    float* __restrict__ H, float* __restrict__ AS, float* __restrict__ AD,
    unsigned* __restrict__ M4) {
  constexpr unsigned BB = K * 144 * 2;               // bytes per B buffer
  constexpr unsigned FB = 128 * 128 * 4 + 128 * 8 * 4;  // bounce tile + AS/AD
  constexpr unsigned SM = (2 * BB > FB) ? 2 * BB : FB;
  __shared__ __align__(16) char smem[SM];
  short* sBh = (short*)smem;
  short* sBl = (short*)(smem + BB);
  const int t = threadIdx.x;
  const int l = t & 63;
  const int w = t >> 6;
  const int m = l & 15;                 // A-row / B-col / D-col selector
  const int g = l >> 4;                 // k-group selector (8 k per group)
  const int row0 = blockIdx.x * 128 + w * 32;  // this wave's 32 rows
  const int row_a = row0 + m;           // tr=0 A row
  const int row_b = row0 + 16 + m;      // tr=1 A row

  // one-time cooperative stage of the whole pre-fragmented B
  for (int i = t; i < K * 18; i += 256) {
    ((bf16x8*)sBh)[i] = ((const bf16x8*)Bh)[i];
    ((bf16x8*)sBl)[i] = ((const bf16x8*)Bl)[i];
  }
  __syncthreads();

  f32x4 acc[2][9];
#pragma unroll
  for (int a = 0; a < 2; ++a)
#pragma unroll
    for (int b = 0; b < 9; ++b) acc[a][b] = (f32x4){0.f, 0.f, 0.f, 0.f};

  float4 pxa0, pxb0, pxa1, pxb1;        // prefetched A (2 row-tiles x 32B)
#define LOADA(kb)                                                              \
  {                                                                            \
    pxa0 = pxb0 = pxa1 = pxb1 = make_float4(0.f, 0.f, 0.f, 0.f);               \
    if (row_a < N_NODES) {                                                     \
      const float4* xp = (const float4*)&X[(size_t)row_a * K + (kb) + g * 8];  \
      pxa0 = xp[0]; pxb0 = xp[1];                                              \
    }                                                                          \
    if (row_b < N_NODES) {                                                     \
      const float4* xp = (const float4*)&X[(size_t)row_b * K + (kb) + g * 8];  \
      pxa1 = xp[0]; pxb1 = xp[1];                                              \
    }                                                                          \
  }

  LOADA(0);
  for (int kb = 0; kb < K; kb += 32) {
    // convert the prefetched A to hi/lo bf16 fragments
    bf16x8 ahi[2], alo[2];
    {
      float xv0[8] = {pxa0.x, pxa0.y, pxa0.z, pxa0.w, pxb0.x, pxb0.y, pxb0.z, pxb0.w};
      float xv1[8] = {pxa1.x, pxa1.y, pxa1.z, pxa1.w, pxb1.x, pxb1.y, pxb1.z, pxb1.w};
#pragma unroll
      for (int j = 0; j < 8; ++j) {
        unsigned short h0 = bf16_rne(xv0[j]);
        ahi[0][j] = (short)h0;
        alo[0][j] = (short)bf16_rne(xv0[j] - __uint_as_float((unsigned)h0 << 16));
        unsigned short h1 = bf16_rne(xv1[j]);
        ahi[1][j] = (short)h1;
        alo[1][j] = (short)bf16_rne(xv1[j] - __uint_as_float((unsigned)h1 << 16));
      }
    }
    if (kb + 32 < K) LOADA(kb + 32);   // issue next chunk's loads now

    // B fragments from LDS, 3-product MFMA per (tr, tc)
    const int kfl = ((kb >> 3) + g) * 144;
#pragma unroll
    for (int tc = 0; tc < 9; ++tc) {
      bf16x8 bh = *(const bf16x8*)(sBh + (kfl + tc * 16 + m) * 8);
      bf16x8 bl = *(const bf16x8*)(sBl + (kfl + tc * 16 + m) * 8);
#pragma unroll
      for (int tr = 0; tr < 2; ++tr) {
        acc[tr][tc] = __builtin_amdgcn_mfma_f32_16x16x32_bf16(ahi[tr], bh, acc[tr][tc], 0, 0, 0);
        acc[tr][tc] = __builtin_amdgcn_mfma_f32_16x16x32_bf16(ahi[tr], bl, acc[tr][tc], 0, 0, 0);
        acc[tr][tc] = __builtin_amdgcn_mfma_f32_16x16x32_bf16(alo[tr], bh, acc[tr][tc], 0, 0, 0);
      }
    }
  }
#undef LOADA

  // per-head AS max from registers (lane l=g*16+m; fold over g via xor16/32)
  float vmax = -3.4e38f;
#pragma unroll
  for (int tr = 0; tr < 2; ++tr)
#pragma unroll
    for (int e = 0; e < 4; ++e) vmax = fmaxf(vmax, acc[tr][8][e]);
  vmax = fmaxf(vmax, __shfl_xor(vmax, 16));
  vmax = fmaxf(vmax, __shfl_xor(vmax, 32));
  if (g == 0 && m < 4) atomicMax(&M4[m], fenc(vmax));

  // ---- LDS bounce: D-layout scatter goes to LDS; global stores coalesced ---
  __syncthreads();                      // all ds_reads of B complete
  float* sF  = (float*)smem;            // [128][128] fp32 tile
  float* sAS = sF + 128 * 128;          // [128][4]
  float* sAD = sAS + 128 * 4;           // [128][4]
  const int wrow0 = w * 32;
#pragma unroll
  for (int tr = 0; tr < 2; ++tr) {
    int rl = wrow0 + tr * 16 + g * 4;   // local row base for this lane
#pragma unroll
    for (int tc = 0; tc < 8; ++tc) {
      int col = tc * 16 + m;
#pragma unroll
      for (int e = 0; e < 4; ++e) sF[(rl + e) * 128 + col] = acc[tr][tc][e];
    }
#pragma unroll
    for (int e = 0; e < 4; ++e) {
      float v = acc[tr][8][e];
      if (m < 4) sAS[(rl + e) * 4 + m] = v;
      else if (m < 8) sAD[(rl + e) * 4 + (m - 4)] = v;
    }
  }
  __syncthreads();
  const int base = blockIdx.x * 128;
  for (int i = t; i < 128 * 32; i += 256) {     // full-line float4 stores
    int r = i >> 5, c4 = (i & 31) << 2;
    int gr = base + r;
    if (gr < N_NODES)
      *(float4*)&H[(size_t)gr * HF + c4] = *(const float4*)&sF[r * 128 + c4];
  }
  {
    int r = t & 127, gr = base + r;
    if (gr < N_NODES) {
      if (t < 128) *(float4*)&AS[(size_t)gr * 4] = *(const float4*)&sAS[r * 4];
      else         *(float4*)&AD[(size_t)gr * 4] = *(const float4*)&sAD[r * 4];
    }
  }
}

// ---------------- fused softmax + aggregation ----------------
// Half-wave (32 lanes) per node: each lane owns 4 columns (float4) of the
// 512B H row. 4 edges unrolled -> independent csr->H gather chains.
template<bool CONCAT>
__global__ void __launch_bounds__(256) k_aggregate(
    const int* __restrict__ rs, const int* __restrict__ csr_src,
    const float* __restrict__ H, const float* __restrict__ AS,
    const float* __restrict__ AD, const unsigned* __restrict__ M4,
    const float* __restrict__ bias, float* __restrict__ OUT) {
  int n = blockIdx.x * 8 + (threadIdx.x >> 5);
  if (n >= N_NODES) return;
  int sl = threadIdx.x & 31;
  int c = sl * 4;                      // this lane's 4 columns
  int head = sl >> 3;
  int b = rs[n], e = rs[n + 1];

  float ad = AD[4 * n + head];
  float m = lrelu(fdec(M4[head]) + ad);

  float ax = 0.f, ay = 0.f, az = 0.f, aw = 0.f, den = 0.f;
  int jj = b;
  for (; jj + 3 < e; jj += 4) {        // 4 gather chains in flight
    int s0 = csr_src[jj];
    int s1 = csr_src[jj + 1];
    int s2 = csr_src[jj + 2];
    int s3 = csr_src[jj + 3];
    float e0 = __expf(lrelu(AS[4 * s0 + head] + ad) - m);
    float e1 = __expf(lrelu(AS[4 * s1 + head] + ad) - m);
    float e2 = __expf(lrelu(AS[4 * s2 + head] + ad) - m);
    float e3 = __expf(lrelu(AS[4 * s3 + head] + ad) - m);
    float4 h0 = *(const float4*)&H[(size_t)s0 * HF + c];
    float4 h1 = *(const float4*)&H[(size_t)s1 * HF + c];
    float4 h2 = *(const float4*)&H[(size_t)s2 * HF + c];
    float4 h3 = *(const float4*)&H[(size_t)s3 * HF + c];
    ax += h0.x * e0 + h1.x * e1 + h2.x * e2 + h3.x * e3;
    ay += h0.y * e0 + h1.y * e1 + h2.y * e2 + h3.y * e3;
    az += h0.z * e0 + h1.z * e1 + h2.z * e2 + h3.z * e3;
    aw += h0.w * e0 + h1.w * e1 + h2.w * e2 + h3.w * e3;
    den += (e0 + e1) + (e2 + e3);
  }
  for (; jj < e; ++jj) {
    int s0 = csr_src[jj];
    float e0 = __expf(lrelu(AS[4 * s0 + head] + ad) - m);
    float4 h0 = *(const float4*)&H[(size_t)s0 * HF + c];
    ax += h0.x * e0; ay += h0.y * e0; az += h0.z * e0; aw += h0.w * e0;
    den += e0;
  }

  float invd = 1.f / den;
  if (CONCAT) {
    float4 o;
    o.x = elu_f(ax * invd + bias[c]);
    o.y = elu_f(ay * invd + bias[c + 1]);
    o.z = elu_f(az * invd + bias[c + 2]);
    o.w = elu_f(aw * invd + bias[c + 3]);
    *(float4*)&OUT[(size_t)n * HF + c] = o;
  } else {
    // mean over heads: fold lanes sl^8, sl^16 (stay within the 32-lane half)
    ax *= invd; ay *= invd; az *= invd; aw *= invd;
    ax += __shfl_xor(ax, 8);  ay += __shfl_xor(ay, 8);
    az += __shfl_xor(az, 8);  aw += __shfl_xor(aw, 8);
    ax += __shfl_xor(ax, 16); ay += __shfl_xor(ay, 16);
    az += __shfl_xor(az, 16); aw += __shfl_xor(aw, 16);
    if (sl < 8) {
      int cc = sl * 4;                 // 0..28
      float4 o;
      o.x = elu_f(0.25f * ax + bias[cc]);
      o.y = elu_f(0.25f * ay + bias[cc + 1]);
      o.z = elu_f(0.25f * az + bias[cc + 2]);
      o.w = elu_f(0.25f * aw + bias[cc + 3]);
      *(float4*)&OUT[(size_t)n * HID + cc] = o;
    }
  }
}

// ---------------- global mean pool + MLP head (one wave per graph) ----------------
__global__ void __launch_bounds__(64) k_pool_mlp(
    const int* __restrict__ batch, const float* __restrict__ H3,
    const float* __restrict__ Wm1, const float* __restrict__ bm1,
    const float* __restrict__ Wm2, const float* __restrict__ bm2,
    float* __restrict__ OUT) {
  int g = blockIdx.x;
  int t = threadIdx.x;
  __shared__ float pooled[HID];
  int lo = 0, hi = N_NODES;
  while (lo < hi) { int mid = (lo + hi) >> 1; if (batch[mid] < g) lo = mid + 1; else hi = mid; }
  int start = lo;
  hi = N_NODES;
  while (lo < hi) { int mid = (lo + hi) >> 1; if (batch[mid] < g + 1) lo = mid + 1; else hi = mid; }
  int end = lo;
  if (t < HID) {
    float s = 0.f;
    for (int n = start; n < end; ++n) s += H3[(size_t)n * HID + t];
    float cnt = (float)(end - start);
    pooled[t] = s / fmaxf(cnt, 1.f);
  }
  __syncthreads();
  float z = bm1[t];
#pragma unroll
  for (int f = 0; f < HID; ++f) z += pooled[f] * Wm1[f * 64 + t];
  z = fmaxf(z, 0.f);
  float p = z * Wm2[t];
  for (int off = 32; off > 0; off >>= 1) p += __shfl_down(p, off);
  if (t == 0) OUT[g] = p + bm2[0];
}

extern "C" void kernel_launch(void* const* d_in, const int* in_sizes, int n_in,
                              void* d_out, int out_size, void* d_ws, size_t ws_size,
                              hipStream_t stream) {
  const float* x    = (const float*)d_in[0];
  const int*   ei   = (const int*)d_in[1];
  const int*   batch= (const int*)d_in[2];
  const float* W1   = (const float*)d_in[3];
  const float* a1s  = (const float*)d_in[4];
  const float* a1d  = (const float*)d_in[5];
  const float* b1   = (const float*)d_in[6];
  const float* W2   = (const float*)d_in[7];
  const float* a2s  = (const float*)d_in[8];
  const float* a2d  = (const float*)d_in[9];
  const float* b2   = (const float*)d_in[10];
  const float* W3   = (const float*)d_in[11];
  const float* a3s  = (const float*)d_in[12];
  const float* a3d  = (const float*)d_in[13];
  const float* b3   = (const float*)d_in[14];
  const float* Wm1  = (const float*)d_in[15];
  const float* bm1  = (const float*)d_in[16];
  const float* Wm2  = (const float*)d_in[17];
  const float* bm2  = (const float*)d_in[18];
  float* out = (float*)d_out;

  char* p = (char*)d_ws;
  auto take = [&](size_t bytes) { char* r = p; p += (bytes + 255) & ~(size_t)255; return r; };
  float*          bufA = (float*)take((size_t)N_NODES * HF * 4);
  float*          bufB = (float*)take((size_t)N_NODES * HF * 4);
  float*          AS   = (float*)take((size_t)N_NODES * HEADS * 4);
  float*          AD   = (float*)take((size_t)N_NODES * HEADS * 4);
  unsigned*       M4   = (unsigned*)take(3 * 4 * 4);        // 3 layers x 4 heads
  int*            deg  = (int*)take((size_t)N_NODES * 4);   // reused as fill counters
  int*            rs   = (int*)take((size_t)(N_NODES + 1) * 4);
  int*            csr  = (int*)take((size_t)ET * 4);
  int*            bsums= (int*)take((size_t)512 * 4);
  unsigned short* Wh1  = (unsigned short*)take((size_t)IN_DIM * 144 * 2);
  unsigned short* Wl1  = (unsigned short*)take((size_t)IN_DIM * 144 * 2);
  unsigned short* Wh2  = (unsigned short*)take((size_t)HF * 144 * 2);
  unsigned short* Wl2  = (unsigned short*)take((size_t)HF * 144 * 2);
  unsigned short* Wh3  = (unsigned short*)take((size_t)HF * 144 * 2);
  unsigned short* Wl3  = (unsigned short*)take((size_t)HF * 144 * 2);

  unsigned* M4a = M4;
  unsigned* M4b = M4 + 4;
  unsigned* M4c = M4 + 8;

  const int nb_scan = (N_NODES + 255) / 256;  // 391

  // weight prep (independent of CSR; tiny)
  k_prep<IN_DIM><<<(IN_DIM * 144 + 255) / 256, 256, 0, stream>>>(W1, a1s, a1d, Wh1, Wl1);
  k_prep<HF><<<(HF * 144 + 255) / 256, 256, 0, stream>>>(W2, a2s, a2d, Wh2, Wl2);
  k_prep<HF><<<(HF * 144 + 255) / 256, 256, 0, stream>>>(W3, a3s, a3d, Wh3, Wl3);

  hipMemsetAsync(deg, 0, (size_t)N_NODES * 4, stream);
  hipMemsetAsync(M4, 0, 48, stream);
  k_count<<<(ET + 255) / 256, 256, 0, stream>>>(ei, deg);
  k_scan1<<<nb_scan, 256, 0, stream>>>(deg, rs, bsums);
  k_scan2<<<1, 512, 0, stream>>>(bsums, nb_scan);
  k_scan3<<<nb_scan, 256, 0, stream>>>(rs, bsums);
  hipMemsetAsync(deg, 0, (size_t)N_NODES * 4, stream);
  k_fill<<<(ET + 255) / 256, 256, 0, stream>>>(ei, rs, deg, csr);

  const int gb = (N_NODES + 127) / 128;       // 782 blocks of 128 rows
  const int ab = (N_NODES + 7) / 8;           // aggregate: 8 nodes/block

  // layer 1 (K=64)
  k_gemm_attn<IN_DIM><<<gb, 256, 0, stream>>>(x, Wh1, Wl1, bufA, AS, AD, M4a);
  k_aggregate<true><<<ab, 256, 0, stream>>>(rs, csr, bufA, AS, AD, M4a, b1, bufB);
  // layer 2 (K=128)
  k_gemm_attn<HF><<<gb, 256, 0, stream>>>(bufB, Wh2, Wl2, bufA, AS, AD, M4b);
  k_aggregate<true><<<ab, 256, 0, stream>>>(rs, csr, bufA, AS, AD, M4b, b2, bufB);
  // layer 3 (K=128, concat=False -> head mean)
  k_gemm_attn<HF><<<gb, 256, 0, stream>>>(bufB, Wh3, Wl3, bufA, AS, AD, M4c);
  k_aggregate<false><<<ab, 256, 0, stream>>>(rs, csr, bufA, AS, AD, M4c, b3, bufB);
  // pool + MLP
  k_pool_mlp<<<N_GRAPHS, 64, 0, stream>>>(batch, bufB, Wm1, bm1, Wm2, bm2, out);
}